// Round 5
// baseline (94.334 us; speedup 1.0000x reference)
//
#include <hip/hip_runtime.h>

// NestedLoop: out = inp * prod_{i=0}^{7}(1 + 28*i) — pure streaming scale.
// R5: L3-residency engineering. Input (256 MiB) == L3 capacity, so caching
// all of it self-thrashes at ~50% retention (R4 measured FETCH = 128 MiB).
// Split: first 3/4 of input (192 MiB) cacheable -> stays L3-resident across
// graph replays (only allocating traffic in the machine); last 1/4 (64 MiB)
// non-temporal streamed. All stores non-temporal (no-allocate, proven R4).
// Steady-state HBM/replay: 64 MiB R + 256 MiB W.

typedef float v4f __attribute__((ext_vector_type(4)));

__global__ __launch_bounds__(256) void NestedLoop_29626684408030_kernel(
    const v4f* __restrict__ in, v4f* __restrict__ out, int n4, int t4) {
    // Constant-folded fp32 loop recurrence for the multiplier (matches the
    // reference's rounding path; all-constant -> folded at compile time).
    float s = 1.0f;
#pragma unroll
    for (int i = 0; i < 8; ++i) {
        float b = s * (float)i;
#pragma unroll
        for (int j = 0; j < 8; ++j) {
            s = s + b * (float)j;
        }
    }

    int idx = blockIdx.x * blockDim.x + threadIdx.x;
    int stride = gridDim.x * blockDim.x;

    // Region 1: [0, t4) — cacheable loads (L3-resident set).
    for (int k = idx; k < t4; k += stride) {
        v4f v = in[k];
        v *= s;
        __builtin_nontemporal_store(v, &out[k]);
    }
    // Region 2: [t4, n4) — non-temporal loads (streamed, no L3 allocate).
    for (int k = t4 + idx; k < n4; k += stride) {
        v4f v = __builtin_nontemporal_load(&in[k]);
        v *= s;
        __builtin_nontemporal_store(v, &out[k]);
    }
}

extern "C" void kernel_launch(void* const* d_in, const int* in_sizes, int n_in,
                              void* d_out, int out_size, void* d_ws, size_t ws_size,
                              hipStream_t stream) {
    const v4f* in = (const v4f*)d_in[0];
    v4f* out = (v4f*)d_out;
    int n = in_sizes[0];          // 67,108,864 floats
    int n4 = n / 4;               // 16,777,216 float4s
    int t4 = (n4 / 4) * 3;        // 3/4 boundary: 12,582,912 float4s = 192 MiB

    const int block = 256;
    int grid = 2048;              // 256 CUs x 8 blocks/CU (32 waves/CU)
    NestedLoop_29626684408030_kernel<<<grid, block, 0, stream>>>(in, out, n4, t4);
}

// Round 6
// 88.373 us; speedup vs baseline: 1.0675x; 1.0675x over previous
//
#include <hip/hip_runtime.h>

// NestedLoop: out = inp * prod_{i=0}^{7}(1 + 28*i) — pure streaming scale.
// R6 = revert to R4 (best: 85.3 us = 512 MiB / 6.29 TB/s, exactly the m13
// measured copy ceiling). Cacheable loads (L3 retains ~half the 256 MiB
// input across graph replays, FETCH 256->128 MiB) + non-temporal stores
// (no-allocate: output never evicts the input from Infinity Cache).
// R5's nt-load split regressed (94.3) — nt loads don't stream cleanly on
// gfx950; keep loads cacheable.

typedef float v4f __attribute__((ext_vector_type(4)));

__global__ __launch_bounds__(256) void NestedLoop_29626684408030_kernel(
    const v4f* __restrict__ in, v4f* __restrict__ out, int n4) {
    // Constant-folded fp32 loop recurrence for the multiplier (matches the
    // reference's rounding path; all-constant -> folded at compile time).
    float s = 1.0f;
#pragma unroll
    for (int i = 0; i < 8; ++i) {
        float b = s * (float)i;
#pragma unroll
        for (int j = 0; j < 8; ++j) {
            s = s + b * (float)j;
        }
    }

    int idx = blockIdx.x * blockDim.x + threadIdx.x;
    int stride = gridDim.x * blockDim.x;
    for (int k = idx; k < n4; k += stride) {
        v4f v = in[k];           // cacheable load — let L3 retain the input
        v *= s;
        __builtin_nontemporal_store(v, &out[k]);  // no-allocate store
    }
}

extern "C" void kernel_launch(void* const* d_in, const int* in_sizes, int n_in,
                              void* d_out, int out_size, void* d_ws, size_t ws_size,
                              hipStream_t stream) {
    const v4f* in = (const v4f*)d_in[0];
    v4f* out = (v4f*)d_out;
    int n = in_sizes[0];          // 67,108,864 floats
    int n4 = n / 4;               // 16,777,216 float4s

    const int block = 256;
    int grid = 2048;              // 256 CUs x 8 blocks/CU (32 waves/CU)
    NestedLoop_29626684408030_kernel<<<grid, block, 0, stream>>>(in, out, n4);
}